// Round 10
// baseline (143.735 us; speedup 1.0000x reference)
//
#include <hip/hip_runtime.h>
#include <math.h>

// ===== ROUND 10: SPLIT THE TWO RANDOM STREAMS (score precompute) =====
// R9 counters: k_fused 52us, FETCH 82MB (vs ~20 ideal), VALU 30%, nothing
// saturated. The 205MB random row-gather (12.8MB set) thrashes per-XCD L2,
// evicting the 200KB a_dst table -> its 800K random 4B loads (on every
// window's dependent chain) become HBM line-fetches. Fix: k_score computes
// all edge scores in a kernel where a_dst has L2 to itself (only random
// stream, 200KB resident), writing sc[e] + packed dst_c[e]. k_fused then
// reads headers SEQUENTIALLY and gathers rows with exclusive L2 use.
// Values bit-identical to R9 (same ops, same order): absmax 0.001953125.
//   k_pre:   WT transpose + u_src/u_dst/cb + rowptr
//   k_att:   a_src/a_dst dots + emb_bf
//   k_score: sc[e] = score(a_src[src]+a_dst[dst]); dst_c[e] = dst
//   k_fused: gather (seq headers) -> LDS agg -> MFMA -> sigmoid -> out

#define NN 50001
#define DD 128
#define NE 800000
#define EDGE_BLOCKS 3125             // ceil(800000/256)
#define ATT_BLOCKS 3126              // ceil(50001/16)
#define TR_BLOCKS 64                 // transpose blocks (2 cols each)
#define ASTRIDE 136                  // LDS agg row stride in shorts (16B-aligned)

typedef __attribute__((ext_vector_type(8))) short short8;
typedef __attribute__((ext_vector_type(4))) float floatx4;

__device__ __forceinline__ unsigned short f2bf(float f) {
    unsigned u = __builtin_bit_cast(unsigned, f);
    u += 0x7fffu + ((u >> 16) & 1u);          // round-to-nearest-even
    return (unsigned short)(u >> 16);
}
__device__ __forceinline__ float bflo(unsigned u) {   // low 16 bits as bf16 -> f32
    return __builtin_bit_cast(float, u << 16);
}
__device__ __forceinline__ float bfhi(unsigned u) {   // high 16 bits as bf16 -> f32
    return __builtin_bit_cast(float, u & 0xffff0000u);
}
__device__ __forceinline__ float score(float att) {   // leaky-relu(0.2) then exp(x-1)
    att = att >= 0.f ? att : 0.2f * att;
    return __expf(att - 1.f);
}

// K0: bx<64: WT[j][k]=bf16(W[k][j]); bx==64: u/c compute; bx>64: rowptr.
__global__ void __launch_bounds__(256) k_pre(const float* __restrict__ W,
        const float* __restrict__ W_att, const float* __restrict__ b_scale,
        const float* __restrict__ b_att, const int* __restrict__ edge,
        unsigned short* __restrict__ WT, float* __restrict__ u_src,
        float* __restrict__ u_dst, float* __restrict__ cb,
        int* __restrict__ row_ptr) {
    if (blockIdx.x < TR_BLOCKS) {
        int j = blockIdx.x * 2 + (threadIdx.x >> 7);    // feature column
        int k = threadIdx.x & 127;                      // contraction index
        WT[j * DD + k] = f2bf(W[k * DD + j]);
        return;
    }
    if (blockIdx.x == TR_BLOCKS) {                      // u_src/u_dst/c (tiny)
        int k = threadIdx.x;
        if (k < DD) {
            float us = 0.f, ud = 0.f;
            for (int j = 0; j < DD; j++) {
                float w = W[k * DD + j];
                us += w * W_att[j];
                ud += w * W_att[DD + j];
            }
            u_src[k] = us; u_dst[k] = ud;
        } else if (k == DD) {
            float c = b_att[0];
            for (int j = 0; j < DD; j++) c += b_scale[j] * W_att[j];
            cb[0] = c;
        } else if (k == DD + 1) {
            float c = 0.f;
            for (int j = 0; j < DD; j++) c += b_scale[j] * W_att[DD + j];
            cb[1] = c;
        }
        return;
    }
    int e = (blockIdx.x - TR_BLOCKS - 1) * 256 + threadIdx.x;
    if (e >= NE) return;
    int s = edge[2 * e];
    if (e == 0) {
        for (int n = 0; n <= s; n++) row_ptr[n] = 0;
    } else {
        int p = edge[2 * (e - 1)];
        for (int n = p + 1; n <= s; n++) row_ptr[n] = e;
    }
    if (e == NE - 1) {
        for (int n = s + 1; n <= NN; n++) row_ptr[n] = NE;
    }
}

// K1: a_src[n]=emb[n].u_src+c0, a_dst=emb.u_dst+c1, emb_bf=bf16(emb). Unchanged.
__global__ void __launch_bounds__(256) k_att(const float* __restrict__ emb,
        const float* __restrict__ u_src, const float* __restrict__ u_dst,
        const float* __restrict__ cb, unsigned short* __restrict__ emb_bf,
        float* __restrict__ a_src, float* __restrict__ a_dst) {
    int n = blockIdx.x * 16 + (threadIdx.x >> 4);
    int t = threadIdx.x & 15;
    if (n >= NN) return;

    const float* ep = emb + (long)n * DD + t * 8;
    float4 e0 = *(const float4*)(ep);
    float4 e1 = *(const float4*)(ep + 4);
    float4 us0 = *(const float4*)(u_src + t * 8);
    float4 us1 = *(const float4*)(u_src + t * 8 + 4);
    float4 ud0 = *(const float4*)(u_dst + t * 8);
    float4 ud1 = *(const float4*)(u_dst + t * 8 + 4);

    float ps = e0.x * us0.x + e0.y * us0.y + e0.z * us0.z + e0.w * us0.w
             + e1.x * us1.x + e1.y * us1.y + e1.z * us1.z + e1.w * us1.w;
    float pd = e0.x * ud0.x + e0.y * ud0.y + e0.z * ud0.z + e0.w * ud0.w
             + e1.x * ud1.x + e1.y * ud1.y + e1.z * ud1.z + e1.w * ud1.w;

    uint4 pk;
    pk.x = (unsigned)f2bf(e0.x) | ((unsigned)f2bf(e0.y) << 16);
    pk.y = (unsigned)f2bf(e0.z) | ((unsigned)f2bf(e0.w) << 16);
    pk.z = (unsigned)f2bf(e1.x) | ((unsigned)f2bf(e1.y) << 16);
    pk.w = (unsigned)f2bf(e1.z) | ((unsigned)f2bf(e1.w) << 16);
    *(uint4*)(emb_bf + (long)n * DD + t * 8) = pk;

    ps += __shfl_xor(ps, 1, 16); ps += __shfl_xor(ps, 2, 16);
    ps += __shfl_xor(ps, 4, 16); ps += __shfl_xor(ps, 8, 16);
    pd += __shfl_xor(pd, 1, 16); pd += __shfl_xor(pd, 2, 16);
    pd += __shfl_xor(pd, 4, 16); pd += __shfl_xor(pd, 8, 16);
    if (t == 0) { a_src[n] = ps + cb[0]; a_dst[n] = pd + cb[1]; }
}

// K1b: per-edge score precompute. Only random stream is a_dst (200KB,
// L2-resident with no competing traffic). src sorted -> a_src ~sequential.
__global__ void __launch_bounds__(256) k_score(const int* __restrict__ edge,
        const float* __restrict__ a_src, const float* __restrict__ a_dst,
        float* __restrict__ sc, int* __restrict__ dst_c) {
    int e = blockIdx.x * 256 + threadIdx.x;
    if (e >= NE) return;
    int2 sd = *(const int2*)(edge + 2 * e);             // coalesced 8B
    sc[e] = score(a_src[sd.x] + a_dst[sd.y]);
    dst_c[e] = sd.y;
}

// K2: fused gather + out-GEMM. Headers (sc, dst_c) read sequentially; the bf16
// row gather is the only random stream. Phase B: MFMA over LDS agg tile.
#define ACC8(S, U) \
    acc[0] += (S) * bflo((U).x); acc[1] += (S) * bfhi((U).x); \
    acc[2] += (S) * bflo((U).y); acc[3] += (S) * bfhi((U).y); \
    acc[4] += (S) * bflo((U).z); acc[5] += (S) * bfhi((U).z); \
    acc[6] += (S) * bflo((U).w); acc[7] += (S) * bfhi((U).w);

__global__ void __launch_bounds__(256) k_fused(const int* __restrict__ row_ptr,
        const float* __restrict__ sc, const int* __restrict__ dst_c,
        const unsigned short* __restrict__ emb_bf,
        const unsigned short* __restrict__ WT, const float* __restrict__ b_scale,
        float* __restrict__ out) {
    __shared__ unsigned short AGG[16 * ASTRIDE];        // 4352 B
    __shared__ int LENS[16];

    int g = threadIdx.x >> 4, t = threadIdx.x & 15;
    int n = blockIdx.x * 16 + g;
    bool nvalid = n < NN;

    int start = 0, len = 0;
    if (nvalid) { start = row_ptr[n]; len = row_ptr[n + 1] - start; }
    if (t == 0) LENS[g] = nvalid ? len : 0;

    uint4 pk = make_uint4(0u, 0u, 0u, 0u);
    if (nvalid && len > 0) {
        const unsigned short* ip = emb_bf + t * 8;

        float acc[8] = {0.f, 0.f, 0.f, 0.f, 0.f, 0.f, 0.f, 0.f};
        float ssum = 0.f;

        for (int j = 0; j < len; j += 16) {
            int jj = j + t;
            int idx = jj < len ? jj : len - 1;
            int d = dst_c[start + idx];        // coalesced 64B per group
            float s = (jj < len) ? sc[start + idx] : 0.f;   // coalesced 64B
            ssum += s;

            int cnt = len - j;
            if (cnt > 16) cnt = 16;
            int kk = 0;
            for (; kk + 8 <= cnt; kk += 8) {   // 8 row-gathers in flight
                int d0 = __shfl(d, kk, 16),     d1 = __shfl(d, kk + 1, 16);
                int d2 = __shfl(d, kk + 2, 16), d3 = __shfl(d, kk + 3, 16);
                int d4 = __shfl(d, kk + 4, 16), d5 = __shfl(d, kk + 5, 16);
                int d6 = __shfl(d, kk + 6, 16), d7 = __shfl(d, kk + 7, 16);
                float s0 = __shfl(s, kk, 16),     s1 = __shfl(s, kk + 1, 16);
                float s2 = __shfl(s, kk + 2, 16), s3 = __shfl(s, kk + 3, 16);
                float s4 = __shfl(s, kk + 4, 16), s5 = __shfl(s, kk + 5, 16);
                float s6 = __shfl(s, kk + 6, 16), s7 = __shfl(s, kk + 7, 16);
                uint4 u0 = *(const uint4*)(ip + (long)d0 * DD);
                uint4 u1 = *(const uint4*)(ip + (long)d1 * DD);
                uint4 u2 = *(const uint4*)(ip + (long)d2 * DD);
                uint4 u3 = *(const uint4*)(ip + (long)d3 * DD);
                uint4 u4 = *(const uint4*)(ip + (long)d4 * DD);
                uint4 u5 = *(const uint4*)(ip + (long)d5 * DD);
                uint4 u6 = *(const uint4*)(ip + (long)d6 * DD);
                uint4 u7 = *(const uint4*)(ip + (long)d7 * DD);
                ACC8(s0, u0); ACC8(s1, u1); ACC8(s2, u2); ACC8(s3, u3);
                ACC8(s4, u4); ACC8(s5, u5); ACC8(s6, u6); ACC8(s7, u7);
            }
            for (; kk + 4 <= cnt; kk += 4) {
                int d0 = __shfl(d, kk, 16),     d1 = __shfl(d, kk + 1, 16);
                int d2 = __shfl(d, kk + 2, 16), d3 = __shfl(d, kk + 3, 16);
                float s0 = __shfl(s, kk, 16),     s1 = __shfl(s, kk + 1, 16);
                float s2 = __shfl(s, kk + 2, 16), s3 = __shfl(s, kk + 3, 16);
                uint4 u0 = *(const uint4*)(ip + (long)d0 * DD);
                uint4 u1 = *(const uint4*)(ip + (long)d1 * DD);
                uint4 u2 = *(const uint4*)(ip + (long)d2 * DD);
                uint4 u3 = *(const uint4*)(ip + (long)d3 * DD);
                ACC8(s0, u0); ACC8(s1, u1); ACC8(s2, u2); ACC8(s3, u3);
            }
            for (; kk < cnt; kk++) {
                int d0 = __shfl(d, kk, 16);
                float s0 = __shfl(s, kk, 16);
                uint4 u0 = *(const uint4*)(ip + (long)d0 * DD);
                ACC8(s0, u0);
            }
        }

        ssum += __shfl_xor(ssum, 1, 16);
        ssum += __shfl_xor(ssum, 2, 16);
        ssum += __shfl_xor(ssum, 4, 16);
        ssum += __shfl_xor(ssum, 8, 16);
        float inv = 1.f / ssum;

        pk.x = (unsigned)f2bf(acc[0] * inv) | ((unsigned)f2bf(acc[1] * inv) << 16);
        pk.y = (unsigned)f2bf(acc[2] * inv) | ((unsigned)f2bf(acc[3] * inv) << 16);
        pk.z = (unsigned)f2bf(acc[4] * inv) | ((unsigned)f2bf(acc[5] * inv) << 16);
        pk.w = (unsigned)f2bf(acc[6] * inv) | ((unsigned)f2bf(acc[7] * inv) << 16);
    }
    *(uint4*)(AGG + g * ASTRIDE + t * 8) = pk;          // 16B aligned
    __syncthreads();

    // ---- Phase B: out = sigmoid(AGG @ W + b_scale); empty nodes -> 0.5 ----
    int wave = threadIdx.x >> 6;                        // ft pair = wave*2, wave*2+1
    int lane = threadIdx.x & 63;
    int m = lane & 15, q = lane >> 4;
    int node = blockIdx.x * 16 + m;
    bool valid = node < NN;
    int lenm = LENS[m];

    short8 b[4];
    #pragma unroll
    for (int ks = 0; ks < 4; ks++)
        b[ks] = *(const short8*)(AGG + m * ASTRIDE + ks * 32 + q * 8);

    #pragma unroll
    for (int f2 = 0; f2 < 2; f2++) {
        int ft = wave * 2 + f2;
        floatx4 acc = {0.f, 0.f, 0.f, 0.f};
        const unsigned short* wrow = WT + (ft * 16 + m) * DD + q * 8;
        #pragma unroll
        for (int ks = 0; ks < 4; ks++) {
            short8 a = *(const short8*)(wrow + ks * 32);
            acc = __builtin_amdgcn_mfma_f32_16x16x32_bf16(a, b[ks], acc, 0, 0, 0);
        }
        if (valid) {
            int fo = ft * 16 + q * 4;
            float4 bs = *(const float4*)(b_scale + fo);
            float4 o;
            if (lenm > 0) {
                o.x = 1.f / (1.f + __expf(-(acc[0] + bs.x)));
                o.y = 1.f / (1.f + __expf(-(acc[1] + bs.y)));
                o.z = 1.f / (1.f + __expf(-(acc[2] + bs.z)));
                o.w = 1.f / (1.f + __expf(-(acc[3] + bs.w)));
            } else {
                o = make_float4(0.5f, 0.5f, 0.5f, 0.5f);
            }
            *(float4*)(out + (long)node * DD + fo) = o;
        }
    }
}

extern "C" void kernel_launch(void* const* d_in, const int* in_sizes, int n_in,
                              void* d_out, int out_size, void* d_ws, size_t ws_size,
                              hipStream_t stream) {
    const int*   edge    = (const int*)d_in[0];
    const float* emb     = (const float*)d_in[1];
    const float* W_scale = (const float*)d_in[2];
    const float* b_scale = (const float*)d_in[3];
    const float* W_att   = (const float*)d_in[4];
    const float* b_att   = (const float*)d_in[5];
    float* out = (float*)d_out;

    char* ws = (char*)d_ws;
    int*            row_ptr = (int*)(ws);                                // 200832 B
    float*          a_src   = (float*)(ws + 200832);                     // 200192 B
    float*          a_dst   = (float*)(ws + 401024);                     // 200192 B
    unsigned short* emb_bf  = (unsigned short*)(ws + 601216);            // 12800256 B
    unsigned short* WT      = (unsigned short*)(ws + 13401472);          // 32768 B
    float*          u_src   = (float*)(ws + 13434240);                   // 512 B
    float*          u_dst   = (float*)(ws + 13434752);                   // 512 B
    float*          cb      = (float*)(ws + 13435264);                   // 256 B
    float*          sc      = (float*)(ws + 13435520);                   // 3200000 B
    int*            dst_c   = (int*)(ws + 16635520);                     // 3200000 B

    k_pre   <<<TR_BLOCKS + 1 + EDGE_BLOCKS, 256, 0, stream>>>(W_scale, W_att, b_scale,
                                                              b_att, edge, WT, u_src,
                                                              u_dst, cb, row_ptr);
    k_att   <<<ATT_BLOCKS,  256, 0, stream>>>(emb, u_src, u_dst, cb, emb_bf,
                                              a_src, a_dst);
    k_score <<<EDGE_BLOCKS, 256, 0, stream>>>(edge, a_src, a_dst, sc, dst_c);
    k_fused <<<ATT_BLOCKS,  256, 0, stream>>>(row_ptr, sc, dst_c, emb_bf,
                                              WT, b_scale, out);
}